// Round 1
// 567.631 us; speedup vs baseline: 1.1283x; 1.1283x over previous
//
#include <hip/hip_runtime.h>
#include <hip/hip_bf16.h>

// Two-phase FeedForward_denoise:
//   K1 (NEW): MFMA bf16-split GEMM for project_in. x and w_in are split into
//       hi/lo bf16 (exact truncated-mantissa split); 3 MFMA terms give
//       fp32-equivalent accuracy. Output transposed through LDS so xc keeps
//       the [B][16 chunks][HW][24] bf16 record layout K2 consumes.
//       Expected store-bound (~201 MB xc write), was VALU/latency-bound 254us.
//   K2: unchanged from round 7 (512 threads, 16x16 tile, grouped 3x3 convs,
//       depthwise 3x3, GELU gating, grouped 1x1 project_out).
// Fallback to the fully-fused kernel if ws_size < 201 MB.

#define T 16
#define R20 20
#define R18 18
#define HW 65536
#define XC_BYTES ((size_t)4 * 16 * HW * 24 * 2)

typedef unsigned short u16;
typedef unsigned int u32;

typedef __attribute__((ext_vector_type(8))) short bf16x8;
typedef __attribute__((ext_vector_type(4))) float f32x4;

__device__ __forceinline__ float bflo(u32 w) {
    union { u32 i; float f; } v; v.i = w << 16; return v.f;
}
__device__ __forceinline__ float bfhi(u32 w) {
    union { u32 i; float f; } v; v.i = w & 0xffff0000u; return v.f;
}
__device__ __forceinline__ float bf2f(u16 u) {
    union { u32 i; float f; } v; v.i = ((u32)u) << 16; return v.f;
}
__device__ __forceinline__ u16 f2bf(float f) {
    union { float f; u32 i; } v; v.f = f;
    u32 x = v.i;
    u32 r = (x + 0x7fffu + ((x >> 16) & 1u)) >> 16;
    return (u16)r;
}
__device__ __forceinline__ float gelu_exact(float v) {
    return 0.5f * v * (1.0f + erff(v * 0.70710678118654752f));
}

// Exact split of two fp32 into packed-bf16 hi (truncated) and lo (residual).
// a = hi + lo with |dropped lo-truncation| ~ 2^-17 relative: fp32-equivalent
// when used as (whi+wlo)*(xhi+xlo) minus the negligible wlo*xlo term.
__device__ __forceinline__ void pack_pair(float a, float b, u32& hi, u32& lo) {
    union { float f; u32 i; } ua, ub, ha, hb, la, lb;
    ua.f = a; ub.f = b;
    ha.i = ua.i & 0xffff0000u;
    hb.i = ub.i & 0xffff0000u;
    hi = (ha.i >> 16) | hb.i;
    la.f = a - ha.f;
    lb.f = b - hb.f;
    lo = (la.i >> 16) | (lb.i & 0xffff0000u);
}

// ---------------------------------------------------------------------------
// K1: MFMA split-bf16 GEMM. Block = 256 thr (4 waves), 64 pixels/block.
//   wave w computes out-channels [64w, 64w+64) x 64 px via 16x16x32 bf16 MFMA
//   (4 ch-subtiles x 4 px-subtiles x 2 k-steps x 3 split terms = 96 MFMA).
//   pn projection (2-ch input) on VALU. Epilogue transposes through
//   s_outT[px][388] so global stores are dense 48B/pixel records.
// ---------------------------------------------------------------------------
__global__ __launch_bounds__(256, 2)
void k1_proj_mfma(const float* __restrict__ xin,   // [4][64][256][256]
                  const float* __restrict__ pnin,  // [4][2][256][256]
                  const float* __restrict__ w_in,  // [256][64]
                  const float* __restrict__ b_in,  // [256]
                  const float* __restrict__ w_pn,  // [128][2]
                  const float* __restrict__ b_pn,  // [128]
                  u16* __restrict__ xc)            // [4][16][HW][24] bf16
{
    __shared__ float s_x[64][65];                  // x tile, pad 65: no 4-way
    __shared__ __align__(16) u16 s_outT[64 * 388]; // [px][k], pad 388 (4-mult)
    __shared__ float s_bin[256];

    const int tid  = threadIdx.x;
    const int b    = blockIdx.y;
    const int px0  = blockIdx.x * 64;
    const int lane = tid & 63;
    const int wid  = tid >> 6;
    const int lr   = lane & 15;        // MFMA row/col-in-16 index
    const int lh   = lane >> 4;        // MFMA k-group / row-group index
    const int CB   = wid * 64;         // this wave's channel base (w_in rows)

    s_bin[tid] = b_in[tid];

    // ---- stage x tile [64 ch][64 px] fp32 (coalesced float4) --------------
    {
        const float* xb = xin + (size_t)b * 64 * HW + px0;
#pragma unroll
        for (int i = 0; i < 4; ++i) {
            int idx = tid + 256 * i;           // 0..1023 float4 slots
            int row = idx >> 4, seg = (idx & 15) * 4;
            float4 v = *(const float4*)(xb + (size_t)row * HW + seg);
            s_x[row][seg + 0] = v.x; s_x[row][seg + 1] = v.y;
            s_x[row][seg + 2] = v.z; s_x[row][seg + 3] = v.w;
        }
    }

    // ---- w fragments: hi/lo bf16, loaded from global (L2-resident) --------
    // A-frag (16x32): lane holds w[CB+16ci + (lane&15)][32ks + 8*(lane>>4)+v]
    bf16x8 whi[4][2], wlo[4][2];
#pragma unroll
    for (int ci = 0; ci < 4; ++ci)
#pragma unroll
        for (int ks = 0; ks < 2; ++ks) {
            const float* wp = w_in + (size_t)(CB + 16 * ci + lr) * 64
                            + 32 * ks + 8 * lh;
            float4 A0 = *(const float4*)wp;
            float4 A1 = *(const float4*)(wp + 4);
            union { u32 u[4]; bf16x8 v; } H, L;
            pack_pair(A0.x, A0.y, H.u[0], L.u[0]);
            pack_pair(A0.z, A0.w, H.u[1], L.u[1]);
            pack_pair(A1.x, A1.y, H.u[2], L.u[2]);
            pack_pair(A1.z, A1.w, H.u[3], L.u[3]);
            whi[ci][ks] = H.v; wlo[ci][ks] = L.v;
        }

    // ---- pn projection on VALU: 128 ch x 64 px, write rows k<128 ----------
    {
        int px = tid & 63;
        float p0 = pnin[(size_t)b * 2 * HW + px0 + px];
        float p1 = pnin[(size_t)b * 2 * HW + HW + px0 + px];
        u16* orow = &s_outT[px * 388];
#pragma unroll
        for (int i = 0; i < 16; ++i) {
            int k = wid * 32 + 2 * i;          // wave-uniform -> scalar loads
            float va = fmaf(w_pn[2 * k],     p0, fmaf(w_pn[2 * k + 1], p1, b_pn[k]));
            float vb = fmaf(w_pn[2 * k + 2], p0, fmaf(w_pn[2 * k + 3], p1, b_pn[k + 1]));
            *(u32*)&orow[k] = (u32)f2bf(va) | ((u32)f2bf(vb) << 16);
        }
    }
    __syncthreads();

    // ---- MFMA main: acc[ci][pj] = W[64ch x 64k] * X[64k x 64px] -----------
    f32x4 acc[4][4];
#pragma unroll
    for (int ci = 0; ci < 4; ++ci)
#pragma unroll
        for (int pj = 0; pj < 4; ++pj)
            acc[ci][pj] = (f32x4){0.f, 0.f, 0.f, 0.f};

#pragma unroll
    for (int pj = 0; pj < 4; ++pj) {
        // B-frag (32x16): lane holds x[32ks + 8*(lane>>4)+v][16pj + (lane&15)]
        bf16x8 xh[2], xl[2];
#pragma unroll
        for (int ks = 0; ks < 2; ++ks) {
            const int rb = 32 * ks + 8 * lh;
            const int cb = 16 * pj + lr;
            float x0 = s_x[rb + 0][cb], x1 = s_x[rb + 1][cb];
            float x2 = s_x[rb + 2][cb], x3 = s_x[rb + 3][cb];
            float x4 = s_x[rb + 4][cb], x5 = s_x[rb + 5][cb];
            float x6 = s_x[rb + 6][cb], x7 = s_x[rb + 7][cb];
            union { u32 u[4]; bf16x8 v; } H, L;
            pack_pair(x0, x1, H.u[0], L.u[0]);
            pack_pair(x2, x3, H.u[1], L.u[1]);
            pack_pair(x4, x5, H.u[2], L.u[2]);
            pack_pair(x6, x7, H.u[3], L.u[3]);
            xh[ks] = H.v; xl[ks] = L.v;
        }
#pragma unroll
        for (int ci = 0; ci < 4; ++ci) {
#pragma unroll
            for (int ks = 0; ks < 2; ++ks) {
                acc[ci][pj] = __builtin_amdgcn_mfma_f32_16x16x32_bf16(
                    whi[ci][ks], xh[ks], acc[ci][pj], 0, 0, 0);
                acc[ci][pj] = __builtin_amdgcn_mfma_f32_16x16x32_bf16(
                    whi[ci][ks], xl[ks], acc[ci][pj], 0, 0, 0);
                acc[ci][pj] = __builtin_amdgcn_mfma_f32_16x16x32_bf16(
                    wlo[ci][ks], xh[ks], acc[ci][pj], 0, 0, 0);
            }
        }
    }

    // ---- epilogue: acc (+bias) -> bf16 -> s_outT rows 128+kk --------------
    // D-frag: value r of tile (ci,pj) is out[kk = CB+16ci+4*lh+r][16pj+lr]
#pragma unroll
    for (int ci = 0; ci < 4; ++ci) {
        const int kk = CB + 16 * ci + 4 * lh;
        float b0 = s_bin[kk + 0], b1 = s_bin[kk + 1];
        float b2 = s_bin[kk + 2], b3 = s_bin[kk + 3];
#pragma unroll
        for (int pj = 0; pj < 4; ++pj) {
            f32x4 a = acc[ci][pj];
            int px = 16 * pj + lr;
            uint2 val;
            val.x = (u32)f2bf(a[0] + b0) | ((u32)f2bf(a[1] + b1) << 16);
            val.y = (u32)f2bf(a[2] + b2) | ((u32)f2bf(a[3] + b3) << 16);
            *(uint2*)&s_outT[px * 388 + 128 + kk] = val;   // 8B aligned
        }
    }
    __syncthreads();

    // ---- gather per-(chunk,px) 24-ch records, dense 48B stores ------------
    {
        const int c  = tid >> 4;       // chunk 0..15
        const int pb = tid & 15;
#pragma unroll
        for (int rec = 0; rec < 4; ++rec) {
            int px = pb + 16 * rec;
            const u16* row = &s_outT[px * 388];
            const int k1o = 12 * c;          // k = 12c + l,      l<12
            const int k2o = 192 + 12 * c;    // k = 12c+192+(l-12), l>=12
            uint2 a0 = *(const uint2*)&row[k1o];
            uint2 a1 = *(const uint2*)&row[k1o + 4];
            uint2 a2 = *(const uint2*)&row[k1o + 8];
            uint2 a3 = *(const uint2*)&row[k2o];
            uint2 a4 = *(const uint2*)&row[k2o + 4];
            uint2 a5 = *(const uint2*)&row[k2o + 8];
            uint4* dst = (uint4*)(xc + ((size_t)(b * 16 + c) * HW + px0 + px) * 24);
            dst[0] = make_uint4(a0.x, a0.y, a1.x, a1.y);
            dst[1] = make_uint4(a2.x, a2.y, a3.x, a3.y);
            dst[2] = make_uint4(a4.x, a4.y, a5.x, a5.y);
        }
    }
}

// ---------------------------------------------------------------------------
// K2: spatial convs + gating + project_out. 512 threads, split-half epilogue.
// (unchanged from round 7)
// ---------------------------------------------------------------------------
__global__ __launch_bounds__(512, 2)
void k2_spatial(const u16* __restrict__ xc,       // [4][16][HW][24] bf16
                const float* __restrict__ w_dw1,  const float* __restrict__ b_dw1,
                const float* __restrict__ w_dw3a, const float* __restrict__ b_dw3a,
                const float* __restrict__ w_dw3b, const float* __restrict__ b_dw3b,
                const float* __restrict__ w_out,  const float* __restrict__ b_out,
                float* __restrict__ outp)         // [4][64][256][256]
{
    __shared__ __align__(8) u16 s_xc[24][R20 * R20];
    __shared__ __align__(8) u16 s_d3a[8][R18 * R18];
    __shared__ __align__(8) u16 s_d1[8][T * T];
    __shared__ __align__(8) u16 s_d3[8][T * T];
    __shared__ float s_wout[64 * 64];   // 16 KB fp32
    __shared__ float s_wd1[8][27];
    __shared__ float s_wd3a[8][27];
    __shared__ float s_wd3b[8][9];
    __shared__ float s_b1[8], s_b3a[8], s_b3b[8];

    const int tid  = threadIdx.x;
    const int half = tid >> 8;          // wave-uniform (waves 0-3 vs 4-7)
    const int pix  = tid & 255;
    const int ox0 = blockIdx.x * T;
    const int oy0 = blockIdx.y * T;
    const int b   = blockIdx.z;

    // stage w_out once (consumed after the first loop-top barrier)
    for (int i = tid; i < 4096; i += 512) s_wout[i] = w_out[i];

    float acc[32];
#pragma unroll
    for (int o = 0; o < 32; ++o) acc[o] = 0.f;

    for (int chunk = 0; chunk < 16; ++chunk) {
        const int c0 = chunk * 4;
        __syncthreads();   // protect s_* reuse across chunks (+ w_out 1st iter)

        // ---- Phase W: stage chunk weights into LDS -------------------------
        {
            int t = tid;
            if (t < 216) {
                int gl = t / 27, idx = t - gl * 27;
                int g = (gl < 4) ? (c0 + gl) : (c0 + 60 + gl);
                s_wd1[gl][idx] = w_dw1[g * 27 + idx];
            } else if (t < 432) {
                int t2 = t - 216;
                int gl = t2 / 27, idx = t2 - gl * 27;
                int g = (gl < 4) ? (c0 + gl) : (c0 + 60 + gl);
                s_wd3a[gl][idx] = w_dw3a[g * 27 + idx];
            } else if (t < 504) {
                int t2 = t - 432;
                int gl = t2 / 9, idx = t2 - gl * 9;
                int g = (gl < 4) ? (c0 + gl) : (c0 + 60 + gl);
                s_wd3b[gl][idx] = w_dw3b[g * 9 + idx];
            } else if (t < 512) {
                int gl = t - 504;
                int g = (gl < 4) ? (c0 + gl) : (c0 + 60 + gl);
                s_b1[gl]  = b_dw1[g];
                s_b3a[gl] = b_dw3a[g];
                s_b3b[gl] = b_dw3b[g];
            }
        }

        // ---- Phase A: 24 xc channels over 20x20 halo (3 dwordx4 / pixel) ---
        if (tid < 400) {
            int py = tid / R20, px = tid - py * R20;
            int gy = oy0 - 2 + py, gx = ox0 - 2 + px;
            union { uint4 q[3]; u16 h[24]; } v;
            if ((unsigned)gy < 256u && (unsigned)gx < 256u) {
                const uint4* src = (const uint4*)(xc +
                    ((size_t)(b * 16 + chunk) * HW + gy * 256 + gx) * 24);
                v.q[0] = src[0]; v.q[1] = src[1]; v.q[2] = src[2];
            } else {
                v.q[0] = make_uint4(0, 0, 0, 0);
                v.q[1] = make_uint4(0, 0, 0, 0);
                v.q[2] = make_uint4(0, 0, 0, 0);
            }
#pragma unroll
            for (int l = 0; l < 24; ++l) s_xc[l][tid] = v.h[l];
        }
        __syncthreads();

        // ---- Phase B1a: d3a (grouped 3x3) over 18x18, 2x2 per thread -------
        for (int task = tid; task < 8 * 81; task += 512) {
            int gl = task / 81, patch = task - gl * 81;
            int py = (patch / 9) * 2, px = (patch - (patch / 9) * 9) * 2;
            float bias = s_b3a[gl];
            float a00 = bias, a01 = bias, a10 = bias, a11 = bias;
#pragma unroll
            for (int j = 0; j < 3; ++j) {
                int lc = (gl < 4) ? (3 * gl + j) : (12 + 3 * (gl - 4) + j);
                const u32* base = (const u32*)&s_xc[lc][0];
                float win[4][4];
#pragma unroll
                for (int r = 0; r < 4; ++r) {
                    int e = (py + r) * R20 + px;   // even
                    u32 u0 = base[e >> 1];
                    u32 u1 = base[(e >> 1) + 1];
                    win[r][0] = bflo(u0); win[r][1] = bfhi(u0);
                    win[r][2] = bflo(u1); win[r][3] = bfhi(u1);
                }
#pragma unroll
                for (int ky = 0; ky < 3; ++ky)
#pragma unroll
                    for (int kx = 0; kx < 3; ++kx) {
                        float wgt = s_wd3a[gl][j * 9 + ky * 3 + kx];
                        a00 = fmaf(wgt, win[ky][kx], a00);
                        a01 = fmaf(wgt, win[ky][kx + 1], a01);
                        a10 = fmaf(wgt, win[ky + 1][kx], a10);
                        a11 = fmaf(wgt, win[ky + 1][kx + 1], a11);
                    }
            }
            int gy0 = oy0 - 1 + py, gx0 = ox0 - 1 + px;
            bool vy0 = (unsigned)gy0 < 256u, vy1 = (unsigned)(gy0 + 1) < 256u;
            bool vx0 = (unsigned)gx0 < 256u, vx1 = (unsigned)(gx0 + 1) < 256u;
            u16* drow = &s_d3a[gl][py * R18 + px];
            drow[0]       = (vy0 && vx0) ? f2bf(a00) : (u16)0;
            drow[1]       = (vy0 && vx1) ? f2bf(a01) : (u16)0;
            drow[R18]     = (vy1 && vx0) ? f2bf(a10) : (u16)0;
            drow[R18 + 1] = (vy1 && vx1) ? f2bf(a11) : (u16)0;
        }

        // ---- Phase B1b: d1 (grouped 3x3), one 2x2 task per thread ----------
        {
            int gl = tid >> 6, patch = tid & 63;
            int py = (patch >> 3) * 2, px = (patch & 7) * 2;
            float bias = s_b1[gl];
            float a00 = bias, a01 = bias, a10 = bias, a11 = bias;
#pragma unroll
            for (int j = 0; j < 3; ++j) {
                int lc = (gl < 4) ? (3 * gl + j) : (12 + 3 * (gl - 4) + j);
                const u32* base = (const u32*)&s_xc[lc][0];
                float win[4][4];
#pragma unroll
                for (int r = 0; r < 4; ++r) {
                    int e = (py + 1 + r) * R20 + px;   // even; cols px+1..px+4
                    u32 u0 = base[e >> 1];
                    u32 u1 = base[(e >> 1) + 1];
                    u32 u2 = base[(e >> 1) + 2];
                    win[r][0] = bfhi(u0); win[r][1] = bflo(u1);
                    win[r][2] = bfhi(u1); win[r][3] = bflo(u2);
                }
#pragma unroll
                for (int ky = 0; ky < 3; ++ky)
#pragma unroll
                    for (int kx = 0; kx < 3; ++kx) {
                        float wgt = s_wd1[gl][j * 9 + ky * 3 + kx];
                        a00 = fmaf(wgt, win[ky][kx], a00);
                        a01 = fmaf(wgt, win[ky][kx + 1], a01);
                        a10 = fmaf(wgt, win[ky + 1][kx], a10);
                        a11 = fmaf(wgt, win[ky + 1][kx + 1], a11);
                    }
            }
            u16* drow = &s_d1[gl][py * T + px];
            drow[0] = f2bf(a00); drow[1] = f2bf(a01);
            drow[T] = f2bf(a10); drow[T + 1] = f2bf(a11);
        }
        __syncthreads();

        // ---- Phase B2: d3 = depthwise 3x3 over d3a, one task per thread ----
        {
            int gl = tid >> 6, patch = tid & 63;
            int py = (patch >> 3) * 2, px = (patch & 7) * 2;
            float bias = s_b3b[gl];
            float a00 = bias, a01 = bias, a10 = bias, a11 = bias;
            float win[4][4];
            const u32* base = (const u32*)&s_d3a[gl][0];
#pragma unroll
            for (int r = 0; r < 4; ++r) {
                int e = (py + r) * R18 + px;   // even
                u32 u0 = base[e >> 1];
                u32 u1 = base[(e >> 1) + 1];
                win[r][0] = bflo(u0); win[r][1] = bfhi(u0);
                win[r][2] = bflo(u1); win[r][3] = bfhi(u1);
            }
#pragma unroll
            for (int ky = 0; ky < 3; ++ky)
#pragma unroll
                for (int kx = 0; kx < 3; ++kx) {
                    float wgt = s_wd3b[gl][ky * 3 + kx];
                    a00 = fmaf(wgt, win[ky][kx], a00);
                    a01 = fmaf(wgt, win[ky][kx + 1], a01);
                    a10 = fmaf(wgt, win[ky + 1][kx], a10);
                    a11 = fmaf(wgt, win[ky + 1][kx + 1], a11);
                }
            u16* drow = &s_d3[gl][py * T + px];
            drow[0] = f2bf(a00); drow[1] = f2bf(a01);
            drow[T] = f2bf(a10); drow[T + 1] = f2bf(a11);
        }
        __syncthreads();

        // ---- Phase C: gating + project_out (half0: d1 gates -> ch 0..31,
        //               half1: d3 gates -> ch 32..63) -----------------------
        {
            const u16* sD = (half == 0) ? &s_d1[0][0] : &s_d3[0][0];
            const float* wrow = s_wout + half * 32 * 64;
#pragma unroll
            for (int jp = 0; jp < 2; ++jp) {
                int j0 = 2 * jp;
                float ga = gelu_exact(bf2f(sD[j0 * 256 + pix]))
                         * bf2f(sD[(j0 + 4) * 256 + pix]);
                float gb = gelu_exact(bf2f(sD[(j0 + 1) * 256 + pix]))
                         * bf2f(sD[(j0 + 5) * 256 + pix]);
                int c = c0 + j0;   // even
#pragma unroll
                for (int o = 0; o < 32; ++o) {
                    float2 w2 = *(const float2*)(wrow + o * 64 + c);
                    acc[o] = fmaf(w2.x, ga, acc[o]);
                    acc[o] = fmaf(w2.y, gb, acc[o]);
                }
            }
        }
    }

    // ---- Epilogue: bias + fp32 store --------------------------------------
    {
        int py = pix >> 4, pxx = pix & 15;
        size_t obase = (size_t)b * 64 * HW + (size_t)(half * 32) * HW
                     + (size_t)(oy0 + py) * 256 + (ox0 + pxx);
#pragma unroll
        for (int o = 0; o < 32; ++o)
            outp[obase + (size_t)o * HW] = acc[o] + b_out[half * 32 + o];
    }
}

// ---------------------------------------------------------------------------
// Fallback: fully-fused kernel (used only if ws_size < 201 MB).
// ---------------------------------------------------------------------------
__global__ __launch_bounds__(256, 2)
void ffd_fused(const float* __restrict__ xin, const float* __restrict__ pnin,
               const float* __restrict__ w_in, const float* __restrict__ b_in,
               const float* __restrict__ w_pn, const float* __restrict__ b_pn,
               const float* __restrict__ w_dw1, const float* __restrict__ b_dw1,
               const float* __restrict__ w_dw3a, const float* __restrict__ b_dw3a,
               const float* __restrict__ w_dw3b, const float* __restrict__ b_dw3b,
               const float* __restrict__ w_out, const float* __restrict__ b_out,
               float* __restrict__ outp)
{
    __shared__ __align__(8) u16 s_xc[24][R20 * R20];
    __shared__ __align__(8) float s_d3a[8][R18 * R18];
    __shared__ float s_d1[8][T * T];
    __shared__ float s_d3[8][T * T];
    __shared__ float s_wd1[8][27];
    __shared__ float s_wd3a[8][27];
    __shared__ float s_wd3b[8][9];
    __shared__ float s_b1[8], s_b3a[8], s_b3b[8];

    const int tid = threadIdx.x;
    const int ox0 = blockIdx.x * T;
    const int oy0 = blockIdx.y * T;
    const int b   = blockIdx.z;

    float accL[32], accH[32];
#pragma unroll
    for (int o = 0; o < 32; ++o) { accL[o] = 0.f; accH[o] = 0.f; }

    for (int chunk = 0; chunk < 16; ++chunk) {
        const int c0 = chunk * 4;
        __syncthreads();

        for (int t = tid; t < 512; t += 256) {
            if (t < 216) {
                int gl = t / 27, idx = t - gl * 27;
                int g = (gl < 4) ? (c0 + gl) : (c0 + 60 + gl);
                s_wd1[gl][idx] = w_dw1[g * 27 + idx];
            } else if (t < 432) {
                int t2 = t - 216;
                int gl = t2 / 27, idx = t2 - gl * 27;
                int g = (gl < 4) ? (c0 + gl) : (c0 + 60 + gl);
                s_wd3a[gl][idx] = w_dw3a[g * 27 + idx];
            } else if (t < 504) {
                int t2 = t - 432;
                int gl = t2 / 9, idx = t2 - gl * 9;
                int g = (gl < 4) ? (c0 + gl) : (c0 + 60 + gl);
                s_wd3b[gl][idx] = w_dw3b[g * 9 + idx];
            } else {
                int gl = t - 504;
                int g = (gl < 4) ? (c0 + gl) : (c0 + 60 + gl);
                s_b1[gl]  = b_dw1[g];
                s_b3a[gl] = b_dw3a[g];
                s_b3b[gl] = b_dw3b[g];
            }
        }

        for (int p = tid; p < R20 * R20; p += 256) {
            int py = p / R20, px = p - py * R20;
            int gy = oy0 - 2 + py, gx = ox0 - 2 + px;
            if ((unsigned)gy >= 256u || (unsigned)gx >= 256u) {
#pragma unroll 1
                for (int l = 0; l < 24; ++l) s_xc[l][p] = 0;
                continue;
            }
            const int off = gy * 256 + gx;
            float xr[64];
            const float* xp = xin + (size_t)b * 64 * HW + off;
#pragma unroll
            for (int c = 0; c < 64; ++c) xr[c] = xp[(size_t)c * HW];
            float p0 = 0.f, p1 = 0.f;
            if (3 * c0 < 128) {
                const float* pp = pnin + (size_t)b * 2 * HW + off;
                p0 = pp[0]; p1 = pp[HW];
            }
#pragma unroll 1
            for (int l = 0; l < 24; ++l) {
                int k = (l < 12) ? (3 * c0 + l) : (3 * c0 + 192 + (l - 12));
                float acc;
                if (k < 128) {
                    acc = b_pn[k] + w_pn[2 * k] * p0 + w_pn[2 * k + 1] * p1;
                } else {
                    int kk = k - 128;
                    acc = b_in[kk];
                    const float2* wr = (const float2*)(w_in + kk * 64);
#pragma unroll
                    for (int i = 0; i < 32; ++i) {
                        float2 w2 = wr[i];
                        acc = fmaf(w2.x, xr[2 * i], acc);
                        acc = fmaf(w2.y, xr[2 * i + 1], acc);
                    }
                }
                s_xc[l][p] = f2bf(acc);
            }
        }
        __syncthreads();

        for (int task = tid; task < 8 * 81; task += 256) {
            int gl = task / 81, patch = task - gl * 81;
            int py = (patch / 9) * 2, px = (patch - (patch / 9) * 9) * 2;
            float bias = s_b3a[gl];
            float a00 = bias, a01 = bias, a10 = bias, a11 = bias;
#pragma unroll
            for (int j = 0; j < 3; ++j) {
                int lc = (gl < 4) ? (3 * gl + j) : (12 + 3 * (gl - 4) + j);
                const u32* base = (const u32*)&s_xc[lc][0];
                float win[4][4];
#pragma unroll
                for (int r = 0; r < 4; ++r) {
                    int e = (py + r) * R20 + px;
                    u32 u0 = base[e >> 1];
                    u32 u1 = base[(e >> 1) + 1];
                    win[r][0] = bflo(u0); win[r][1] = bfhi(u0);
                    win[r][2] = bflo(u1); win[r][3] = bfhi(u1);
                }
#pragma unroll
                for (int ky = 0; ky < 3; ++ky)
#pragma unroll
                    for (int kx = 0; kx < 3; ++kx) {
                        float wgt = s_wd3a[gl][j * 9 + ky * 3 + kx];
                        a00 = fmaf(wgt, win[ky][kx], a00);
                        a01 = fmaf(wgt, win[ky][kx + 1], a01);
                        a10 = fmaf(wgt, win[ky + 1][kx], a10);
                        a11 = fmaf(wgt, win[ky + 1][kx + 1], a11);
                    }
            }
            int gy0 = oy0 - 1 + py, gx0 = ox0 - 1 + px;
            bool vy0 = (unsigned)gy0 < 256u, vy1 = (unsigned)(gy0 + 1) < 256u;
            bool vx0 = (unsigned)gx0 < 256u, vx1 = (unsigned)(gx0 + 1) < 256u;
            float* drow = &s_d3a[gl][py * R18 + px];
            drow[0]       = (vy0 && vx0) ? a00 : 0.f;
            drow[1]       = (vy0 && vx1) ? a01 : 0.f;
            drow[R18]     = (vy1 && vx0) ? a10 : 0.f;
            drow[R18 + 1] = (vy1 && vx1) ? a11 : 0.f;
        }

        for (int task = tid; task < 8 * 64; task += 256) {
            int gl = task >> 6, patch = task & 63;
            int py = (patch >> 3) * 2, px = (patch & 7) * 2;
            float bias = s_b1[gl];
            float a00 = bias, a01 = bias, a10 = bias, a11 = bias;
#pragma unroll
            for (int j = 0; j < 3; ++j) {
                int lc = (gl < 4) ? (3 * gl + j) : (12 + 3 * (gl - 4) + j);
                const u32* base = (const u32*)&s_xc[lc][0];
                float win[4][4];
#pragma unroll
                for (int r = 0; r < 4; ++r) {
                    int e = (py + 1 + r) * R20 + px;
                    u32 u0 = base[e >> 1];
                    u32 u1 = base[(e >> 1) + 1];
                    u32 u2 = base[(e >> 1) + 2];
                    win[r][0] = bfhi(u0); win[r][1] = bflo(u1);
                    win[r][2] = bfhi(u1); win[r][3] = bflo(u2);
                }
#pragma unroll
                for (int ky = 0; ky < 3; ++ky)
#pragma unroll
                    for (int kx = 0; kx < 3; ++kx) {
                        float wgt = s_wd1[gl][j * 9 + ky * 3 + kx];
                        a00 = fmaf(wgt, win[ky][kx], a00);
                        a01 = fmaf(wgt, win[ky][kx + 1], a01);
                        a10 = fmaf(wgt, win[ky + 1][kx], a10);
                        a11 = fmaf(wgt, win[ky + 1][kx + 1], a11);
                    }
            }
            float* drow = &s_d1[gl][py * T + px];
            drow[0] = a00; drow[1] = a01; drow[T] = a10; drow[T + 1] = a11;
        }
        __syncthreads();

        for (int task = tid; task < 8 * 64; task += 256) {
            int gl = task >> 6, patch = task & 63;
            int py = (patch >> 3) * 2, px = (patch & 7) * 2;
            float bias = s_b3b[gl];
            float a00 = bias, a01 = bias, a10 = bias, a11 = bias;
            float win[4][4];
#pragma unroll
            for (int r = 0; r < 4; ++r) {
                int e = (py + r) * R18 + px;
                float2 f0 = *(const float2*)&s_d3a[gl][e];
                float2 f1 = *(const float2*)&s_d3a[gl][e + 2];
                win[r][0] = f0.x; win[r][1] = f0.y;
                win[r][2] = f1.x; win[r][3] = f1.y;
            }
#pragma unroll
            for (int ky = 0; ky < 3; ++ky)
#pragma unroll
                for (int kx = 0; kx < 3; ++kx) {
                    float wgt = s_wd3b[gl][ky * 3 + kx];
                    a00 = fmaf(wgt, win[ky][kx], a00);
                    a01 = fmaf(wgt, win[ky][kx + 1], a01);
                    a10 = fmaf(wgt, win[ky + 1][kx], a10);
                    a11 = fmaf(wgt, win[ky + 1][kx + 1], a11);
                }
            float* drow = &s_d3[gl][py * T + px];
            drow[0] = a00; drow[1] = a01; drow[T] = a10; drow[T + 1] = a11;
        }
        __syncthreads();

#pragma unroll
        for (int jp = 0; jp < 2; ++jp) {
            int j0 = 2 * jp;
            float g1a = gelu_exact(s_d1[j0][tid])     * s_d1[j0 + 4][tid];
            float g1b = gelu_exact(s_d1[j0 + 1][tid]) * s_d1[j0 + 5][tid];
            float g2a = gelu_exact(s_d3[j0][tid])     * s_d3[j0 + 4][tid];
            float g2b = gelu_exact(s_d3[j0 + 1][tid]) * s_d3[j0 + 5][tid];
            int c = c0 + j0;
#pragma unroll
            for (int o = 0; o < 32; ++o) {
                float2 wL = *(const float2*)(w_out + o * 64 + c);
                accL[o] = fmaf(wL.x, g1a, accL[o]);
                accL[o] = fmaf(wL.y, g1b, accL[o]);
                float2 wH = *(const float2*)(w_out + (o + 32) * 64 + c);
                accH[o] = fmaf(wH.x, g2a, accH[o]);
                accH[o] = fmaf(wH.y, g2b, accH[o]);
            }
        }
    }

    {
        int py = tid >> 4, pxx = tid & 15;
        size_t obase = (size_t)b * 64 * HW
                     + (size_t)(oy0 + py) * 256 + (ox0 + pxx);
#pragma unroll
        for (int o = 0; o < 32; ++o) {
            outp[obase + (size_t)o * HW]        = accL[o] + b_out[o];
            outp[obase + (size_t)(o + 32) * HW] = accH[o] + b_out[o + 32];
        }
    }
}

extern "C" void kernel_launch(void* const* d_in, const int* in_sizes, int n_in,
                              void* d_out, int out_size, void* d_ws, size_t ws_size,
                              hipStream_t stream) {
    (void)in_sizes; (void)n_in; (void)out_size;
    const float* xin    = (const float*)d_in[0];
    const float* pnin   = (const float*)d_in[1];
    const float* w_in   = (const float*)d_in[2];
    const float* b_in   = (const float*)d_in[3];
    const float* w_pn   = (const float*)d_in[4];
    const float* b_pn   = (const float*)d_in[5];
    const float* w_dw1  = (const float*)d_in[6];
    const float* b_dw1  = (const float*)d_in[7];
    const float* w_dw3a = (const float*)d_in[8];
    const float* b_dw3a = (const float*)d_in[9];
    const float* w_dw3b = (const float*)d_in[10];
    const float* b_dw3b = (const float*)d_in[11];
    const float* w_out  = (const float*)d_in[12];
    const float* b_out  = (const float*)d_in[13];
    float* outp = (float*)d_out;

    if (ws_size >= XC_BYTES) {
        u16* xc = (u16*)d_ws;
        dim3 g1(1024, 4), b1(256);   // 64 px/block, MFMA split-bf16
        k1_proj_mfma<<<g1, b1, 0, stream>>>(xin, pnin, w_in, b_in, w_pn, b_pn, xc);
        dim3 g2(16, 16, 4), b2(512);
        k2_spatial<<<g2, b2, 0, stream>>>(xc, w_dw1, b_dw1, w_dw3a, b_dw3a,
                                          w_dw3b, b_dw3b, w_out, b_out, outp);
    } else {
        dim3 grid(16, 16, 4), blk(256);
        ffd_fused<<<grid, blk, 0, stream>>>(xin, pnin, w_in, b_in, w_pn, b_pn,
                                            w_dw1, b_dw1, w_dw3a, b_dw3a,
                                            w_dw3b, b_dw3b, w_out, b_out, outp);
    }
}

// Round 4
// 507.220 us; speedup vs baseline: 1.2627x; 1.1191x over previous
//
#include <hip/hip_runtime.h>
#include <hip/hip_bf16.h>

// Two-phase FeedForward_denoise:
//   K1: MFMA split-bf16 GEMM for project_in, DIRECT global stores:
//       each D-frag quad (4 consecutive channels, 4-aligned) maps to one
//       8B-aligned segment of the [chunk][px][24ch] record, so no LDS
//       transpose is needed. One barrier, 17.6 KB LDS.
//   K2: + chunk+1 halo prefetch into regs (hide HBM-miss latency),
//       erf via branch-free A&S poly (~1e-6 err), phase-C packed FMA
//       (v_pk_fma_f32 via f32x2) with transposed s_woutT[c][o].
//   r4: launch_bounds reverted to the hardware-validated (512,2) — the
//       only untested knob from r2 after two infra-failed rounds.
// Fallback to the fully-fused kernel if ws_size < 201 MB.

#define T 16
#define R20 20
#define R18 18
#define HW 65536
#define XC_BYTES ((size_t)4 * 16 * HW * 24 * 2)

typedef unsigned short u16;
typedef unsigned int u32;

typedef __attribute__((ext_vector_type(8))) short bf16x8;
typedef __attribute__((ext_vector_type(4))) float f32x4;
typedef __attribute__((ext_vector_type(2))) float f32x2;

__device__ __forceinline__ float bflo(u32 w) {
    union { u32 i; float f; } v; v.i = w << 16; return v.f;
}
__device__ __forceinline__ float bfhi(u32 w) {
    union { u32 i; float f; } v; v.i = w & 0xffff0000u; return v.f;
}
__device__ __forceinline__ float bf2f(u16 u) {
    union { u32 i; float f; } v; v.i = ((u32)u) << 16; return v.f;
}
__device__ __forceinline__ u16 f2bf(float f) {
    union { float f; u32 i; } v; v.f = f;
    u32 x = v.i;
    u32 r = (x + 0x7fffu + ((x >> 16) & 1u)) >> 16;
    return (u16)r;
}
__device__ __forceinline__ u32 f2bf2(float a, float b) {
    return (u32)f2bf(a) | ((u32)f2bf(b) << 16);
}
__device__ __forceinline__ float gelu_exact(float v) {
    return 0.5f * v * (1.0f + erff(v * 0.70710678118654752f));
}
// Branch-free erf, A&S 7.1.26 (|err| ~1e-6 in fp32) — inputs here are
// bf16-rounded already (2^-9 rel), so approximation error is negligible.
__device__ __forceinline__ float erf_fast(float x) {
    float ax = fabsf(x);
    float t = __builtin_amdgcn_rcpf(fmaf(0.3275911f, ax, 1.0f));
    float p = fmaf(t, 1.061405429f, -1.453152027f);
    p = fmaf(t, p, 1.421413741f);
    p = fmaf(t, p, -0.284496736f);
    p = fmaf(t, p, 0.254829592f);
    p = p * t;
    float e = __expf(-ax * ax);
    float r = fmaf(-p, e, 1.0f);
    return copysignf(r, x);
}
__device__ __forceinline__ float gelu_fast(float v) {
    return 0.5f * v * (1.0f + erf_fast(v * 0.70710678118654752f));
}

// Exact split of two fp32 into packed-bf16 hi (truncated) and lo (residual).
__device__ __forceinline__ void pack_pair(float a, float b, u32& hi, u32& lo) {
    union { float f; u32 i; } ua, ub, ha, hb, la, lb;
    ua.f = a; ub.f = b;
    ha.i = ua.i & 0xffff0000u;
    hb.i = ub.i & 0xffff0000u;
    hi = (ha.i >> 16) | hb.i;
    la.f = a - ha.f;
    lb.f = b - hb.f;
    lo = (la.i >> 16) | (lb.i & 0xffff0000u);
}

// ---------------------------------------------------------------------------
// K1: MFMA split-bf16 GEMM, direct global stores. 256 thr, 64 px/block.
//   wave w computes out-channels [64w,64w+64) x 64 px; D-frag quads are
//   stored straight into the xc records (8B each, 8B-aligned).
// ---------------------------------------------------------------------------
__global__ __launch_bounds__(256, 2)
void k1_proj_mfma(const float* __restrict__ xin,   // [4][64][256][256]
                  const float* __restrict__ pnin,  // [4][2][256][256]
                  const float* __restrict__ w_in,  // [256][64]
                  const float* __restrict__ b_in,  // [256]
                  const float* __restrict__ w_pn,  // [128][2]
                  const float* __restrict__ b_pn,  // [128]
                  u16* __restrict__ xc)            // [4][16][HW][24] bf16
{
    __shared__ float s_x[64][65];                  // x tile, pad 65
    __shared__ float s_bin[256];

    const int tid  = threadIdx.x;
    const int b    = blockIdx.y;
    const int px0  = blockIdx.x * 64;
    const int lane = tid & 63;
    const int wid  = tid >> 6;
    const int lr   = lane & 15;        // MFMA row/col-in-16 index
    const int lh   = lane >> 4;        // MFMA k-group / row-group index
    const int CB   = wid * 64;         // this wave's channel base (w_in rows)

    s_bin[tid] = b_in[tid];

    // ---- stage x tile [64 ch][64 px] fp32 (coalesced float4) --------------
    {
        const float* xb = xin + (size_t)b * 64 * HW + px0;
#pragma unroll
        for (int i = 0; i < 4; ++i) {
            int idx = tid + 256 * i;           // 0..1023 float4 slots
            int row = idx >> 4, seg = (idx & 15) * 4;
            float4 v = *(const float4*)(xb + (size_t)row * HW + seg);
            s_x[row][seg + 0] = v.x; s_x[row][seg + 1] = v.y;
            s_x[row][seg + 2] = v.z; s_x[row][seg + 3] = v.w;
        }
    }

    // ---- w fragments: hi/lo bf16, loaded from global (L2-resident) --------
    bf16x8 whi[4][2], wlo[4][2];
#pragma unroll
    for (int ci = 0; ci < 4; ++ci)
#pragma unroll
        for (int ks = 0; ks < 2; ++ks) {
            const float* wp = w_in + (size_t)(CB + 16 * ci + lr) * 64
                            + 32 * ks + 8 * lh;
            float4 A0 = *(const float4*)wp;
            float4 A1 = *(const float4*)(wp + 4);
            union { u32 u[4]; bf16x8 v; } H, L;
            pack_pair(A0.x, A0.y, H.u[0], L.u[0]);
            pack_pair(A0.z, A0.w, H.u[1], L.u[1]);
            pack_pair(A1.x, A1.y, H.u[2], L.u[2]);
            pack_pair(A1.z, A1.w, H.u[3], L.u[3]);
            whi[ci][ks] = H.v; wlo[ci][ks] = L.v;
        }

    // ---- pn projection: 128 ch x 64 px, direct 8B stores (pre-barrier) ----
    {
        const int wu = __builtin_amdgcn_readfirstlane(wid);
        const int px = lane;
        float p0 = pnin[(size_t)b * 2 * HW + px0 + px];
        float p1 = pnin[(size_t)b * 2 * HW + HW + px0 + px];
#pragma unroll
        for (int q = 0; q < 8; ++q) {
            int k = 32 * wu + 4 * q;           // wave-uniform quad base, <128
            int c = k / 12, l = k - 12 * c;    // l in {0,4,8}
            float v0 = fmaf(w_pn[2*k+0], p0, fmaf(w_pn[2*k+1], p1, b_pn[k+0]));
            float v1 = fmaf(w_pn[2*k+2], p0, fmaf(w_pn[2*k+3], p1, b_pn[k+1]));
            float v2 = fmaf(w_pn[2*k+4], p0, fmaf(w_pn[2*k+5], p1, b_pn[k+2]));
            float v3 = fmaf(w_pn[2*k+6], p0, fmaf(w_pn[2*k+7], p1, b_pn[k+3]));
            uint2 val;
            val.x = f2bf2(v0, v1);
            val.y = f2bf2(v2, v3);
            *(uint2*)(xc + ((size_t)(b * 16 + c) * HW + px0 + px) * 24 + l) = val;
        }
    }
    __syncthreads();

    // ---- MFMA main: acc[ci][pj] = W[64ch x 64k] * X[64k x 64px] -----------
    f32x4 acc[4][4];
#pragma unroll
    for (int ci = 0; ci < 4; ++ci)
#pragma unroll
        for (int pj = 0; pj < 4; ++pj)
            acc[ci][pj] = (f32x4){0.f, 0.f, 0.f, 0.f};

#pragma unroll
    for (int pj = 0; pj < 4; ++pj) {
        bf16x8 xh[2], xl[2];
#pragma unroll
        for (int ks = 0; ks < 2; ++ks) {
            const int rb = 32 * ks + 8 * lh;
            const int cb = 16 * pj + lr;
            float x0 = s_x[rb + 0][cb], x1 = s_x[rb + 1][cb];
            float x2 = s_x[rb + 2][cb], x3 = s_x[rb + 3][cb];
            float x4 = s_x[rb + 4][cb], x5 = s_x[rb + 5][cb];
            float x6 = s_x[rb + 6][cb], x7 = s_x[rb + 7][cb];
            union { u32 u[4]; bf16x8 v; } H, L;
            pack_pair(x0, x1, H.u[0], L.u[0]);
            pack_pair(x2, x3, H.u[1], L.u[1]);
            pack_pair(x4, x5, H.u[2], L.u[2]);
            pack_pair(x6, x7, H.u[3], L.u[3]);
            xh[ks] = H.v; xl[ks] = L.v;
        }
#pragma unroll
        for (int ci = 0; ci < 4; ++ci) {
#pragma unroll
            for (int ks = 0; ks < 2; ++ks) {
                acc[ci][pj] = __builtin_amdgcn_mfma_f32_16x16x32_bf16(
                    whi[ci][ks], xh[ks], acc[ci][pj], 0, 0, 0);
                acc[ci][pj] = __builtin_amdgcn_mfma_f32_16x16x32_bf16(
                    whi[ci][ks], xl[ks], acc[ci][pj], 0, 0, 0);
                acc[ci][pj] = __builtin_amdgcn_mfma_f32_16x16x32_bf16(
                    wlo[ci][ks], xh[ks], acc[ci][pj], 0, 0, 0);
            }
        }
    }

    // ---- epilogue: bias + bf16 + DIRECT stores ----------------------------
    // D-frag: value r of tile (ci,pj) is out[kk = CB+16ci+4*lh+r][16pj+lr].
    // Global k = kk+128; quad maps to one record segment:
    //   kk<64:  c=(kk+128)/12, l=(kk+128)%12 in {0,4,8}
    //   kk>=64: c=(kk-64)/12,  l=12+(kk-64)%12 in {12,16,20}
#pragma unroll
    for (int ci = 0; ci < 4; ++ci) {
        const int kk = CB + 16 * ci + 4 * lh;
        float b0 = s_bin[kk + 0], b1 = s_bin[kk + 1];
        float b2 = s_bin[kk + 2], b3 = s_bin[kk + 3];
        int c, l;
        int kg = kk + 128;
        if (kg < 192) { c = kg / 12; l = kg - 12 * c; }
        else { int t2 = kg - 192; int cq = t2 / 12; c = cq; l = 12 + (t2 - 12 * cq); }
        u16* rec = xc + ((size_t)(b * 16 + c) * HW + px0) * 24 + l;
#pragma unroll
        for (int pj = 0; pj < 4; ++pj) {
            f32x4 a = acc[ci][pj];
            uint2 val;
            val.x = f2bf2(a[0] + b0, a[1] + b1);
            val.y = f2bf2(a[2] + b2, a[3] + b3);
            *(uint2*)(rec + (size_t)(16 * pj + lr) * 24) = val;
        }
    }
}

// ---------------------------------------------------------------------------
// K2: spatial convs + gating + project_out. 512 threads, split-half epilogue.
// halo prefetch (T14), erf_fast, packed-FMA phase C via s_woutT[c][o].
// ---------------------------------------------------------------------------
__global__ __launch_bounds__(512, 2)
void k2_spatial(const u16* __restrict__ xc,       // [4][16][HW][24] bf16
                const float* __restrict__ w_dw1,  const float* __restrict__ b_dw1,
                const float* __restrict__ w_dw3a, const float* __restrict__ b_dw3a,
                const float* __restrict__ w_dw3b, const float* __restrict__ b_dw3b,
                const float* __restrict__ w_out,  const float* __restrict__ b_out,
                float* __restrict__ outp)         // [4][64][256][256]
{
    __shared__ __align__(8) u16 s_xc[24][R20 * R20];
    __shared__ __align__(8) u16 s_d3a[8][R18 * R18];
    __shared__ __align__(8) u16 s_d1[8][T * T];
    __shared__ __align__(8) u16 s_d3[8][T * T];
    __shared__ float s_woutT[64 * 66];  // transposed [c][o], pad 66 (8B align)
    __shared__ float s_wd1[8][27];
    __shared__ float s_wd3a[8][27];
    __shared__ float s_wd3b[8][9];
    __shared__ float s_b1[8], s_b3a[8], s_b3b[8];

    const int tid  = threadIdx.x;
    const int half = tid >> 8;          // wave-uniform (waves 0-3 vs 4-7)
    const int pix  = tid & 255;
    const int ox0 = blockIdx.x * T;
    const int oy0 = blockIdx.y * T;
    const int b   = blockIdx.z;
    const int ob  = half * 32;          // output-channel base

    // stage w_out transposed once (consumed after the first loop-top barrier)
    for (int i = tid; i < 4096; i += 512) {
        int o = i >> 6, c = i & 63;
        s_woutT[c * 66 + o] = w_out[i];
    }

    // ---- halo prefetch state (chunk-invariant coords) ---------------------
    int hpy = tid / R20, hpx = tid - hpy * R20;     // meaningful for tid<400
    int hgy = oy0 - 2 + hpy, hgx = ox0 - 2 + hpx;
    const bool pvalid = (tid < 400) &&
                        ((unsigned)hgy < 256u) && ((unsigned)hgx < 256u);
    const u16* psrc = xc + ((size_t)(b * 16) * HW
                            + (pvalid ? (hgy * 256 + hgx) : 0)) * 24;
    uint4 pv0, pv1, pv2;                             // chunk's halo record
    pv0 = pv1 = pv2 = make_uint4(0, 0, 0, 0);
    if (pvalid) {
        const uint4* s = (const uint4*)psrc;
        pv0 = s[0]; pv1 = s[1]; pv2 = s[2];
    }

    f32x2 acc2[16];
#pragma unroll
    for (int o = 0; o < 16; ++o) acc2[o] = (f32x2){0.f, 0.f};

    for (int chunk = 0; chunk < 16; ++chunk) {
        const int c0 = chunk * 4;
        __syncthreads();   // protect s_* reuse across chunks (+ w_out 1st iter)

        // ---- Phase W: stage chunk weights into LDS -------------------------
        {
            int t = tid;
            if (t < 216) {
                int gl = t / 27, idx = t - gl * 27;
                int g = (gl < 4) ? (c0 + gl) : (c0 + 60 + gl);
                s_wd1[gl][idx] = w_dw1[g * 27 + idx];
            } else if (t < 432) {
                int t2 = t - 216;
                int gl = t2 / 27, idx = t2 - gl * 27;
                int g = (gl < 4) ? (c0 + gl) : (c0 + 60 + gl);
                s_wd3a[gl][idx] = w_dw3a[g * 27 + idx];
            } else if (t < 504) {
                int t2 = t - 432;
                int gl = t2 / 9, idx = t2 - gl * 9;
                int g = (gl < 4) ? (c0 + gl) : (c0 + 60 + gl);
                s_wd3b[gl][idx] = w_dw3b[g * 9 + idx];
            } else if (t < 512) {
                int gl = t - 504;
                int g = (gl < 4) ? (c0 + gl) : (c0 + 60 + gl);
                s_b1[gl]  = b_dw1[g];
                s_b3a[gl] = b_dw3a[g];
                s_b3b[gl] = b_dw3b[g];
            }
        }

        // ---- Phase A: write prefetched halo, then issue chunk+1 loads ------
        if (tid < 400) {
            union { uint4 q[3]; u16 h[24]; } v;
            v.q[0] = pv0; v.q[1] = pv1; v.q[2] = pv2;
#pragma unroll
            for (int l = 0; l < 24; ++l) s_xc[l][tid] = v.h[l];
        }
        {
            uint4 n0, n1, n2;
            n0 = n1 = n2 = make_uint4(0, 0, 0, 0);
            if (pvalid && chunk < 15) {
                const uint4* s = (const uint4*)(psrc
                                 + (size_t)(chunk + 1) * HW * 24);
                n0 = s[0]; n1 = s[1]; n2 = s[2];
            }
            pv0 = n0; pv1 = n1; pv2 = n2;   // waitcnt lands at next-iter use
        }
        __syncthreads();

        // ---- Phase B1a: d3a (grouped 3x3) over 18x18, 2x2 per thread -------
        for (int task = tid; task < 8 * 81; task += 512) {
            int gl = task / 81, patch = task - gl * 81;
            int py = (patch / 9) * 2, px = (patch - (patch / 9) * 9) * 2;
            float bias = s_b3a[gl];
            float a00 = bias, a01 = bias, a10 = bias, a11 = bias;
#pragma unroll
            for (int j = 0; j < 3; ++j) {
                int lc = (gl < 4) ? (3 * gl + j) : (12 + 3 * (gl - 4) + j);
                const u32* base = (const u32*)&s_xc[lc][0];
                float win[4][4];
#pragma unroll
                for (int r = 0; r < 4; ++r) {
                    int e = (py + r) * R20 + px;   // even
                    u32 u0 = base[e >> 1];
                    u32 u1 = base[(e >> 1) + 1];
                    win[r][0] = bflo(u0); win[r][1] = bfhi(u0);
                    win[r][2] = bflo(u1); win[r][3] = bfhi(u1);
                }
#pragma unroll
                for (int ky = 0; ky < 3; ++ky)
#pragma unroll
                    for (int kx = 0; kx < 3; ++kx) {
                        float wgt = s_wd3a[gl][j * 9 + ky * 3 + kx];
                        a00 = fmaf(wgt, win[ky][kx], a00);
                        a01 = fmaf(wgt, win[ky][kx + 1], a01);
                        a10 = fmaf(wgt, win[ky + 1][kx], a10);
                        a11 = fmaf(wgt, win[ky + 1][kx + 1], a11);
                    }
            }
            int gy0 = oy0 - 1 + py, gx0 = ox0 - 1 + px;
            bool vy0 = (unsigned)gy0 < 256u, vy1 = (unsigned)(gy0 + 1) < 256u;
            bool vx0 = (unsigned)gx0 < 256u, vx1 = (unsigned)(gx0 + 1) < 256u;
            u16* drow = &s_d3a[gl][py * R18 + px];
            drow[0]       = (vy0 && vx0) ? f2bf(a00) : (u16)0;
            drow[1]       = (vy0 && vx1) ? f2bf(a01) : (u16)0;
            drow[R18]     = (vy1 && vx0) ? f2bf(a10) : (u16)0;
            drow[R18 + 1] = (vy1 && vx1) ? f2bf(a11) : (u16)0;
        }

        // ---- Phase B1b: d1 (grouped 3x3), one 2x2 task per thread ----------
        {
            int gl = tid >> 6, patch = tid & 63;
            int py = (patch >> 3) * 2, px = (patch & 7) * 2;
            float bias = s_b1[gl];
            float a00 = bias, a01 = bias, a10 = bias, a11 = bias;
#pragma unroll
            for (int j = 0; j < 3; ++j) {
                int lc = (gl < 4) ? (3 * gl + j) : (12 + 3 * (gl - 4) + j);
                const u32* base = (const u32*)&s_xc[lc][0];
                float win[4][4];
#pragma unroll
                for (int r = 0; r < 4; ++r) {
                    int e = (py + 1 + r) * R20 + px;   // even; cols px+1..px+4
                    u32 u0 = base[e >> 1];
                    u32 u1 = base[(e >> 1) + 1];
                    u32 u2 = base[(e >> 1) + 2];
                    win[r][0] = bfhi(u0); win[r][1] = bflo(u1);
                    win[r][2] = bfhi(u1); win[r][3] = bflo(u2);
                }
#pragma unroll
                for (int ky = 0; ky < 3; ++ky)
#pragma unroll
                    for (int kx = 0; kx < 3; ++kx) {
                        float wgt = s_wd1[gl][j * 9 + ky * 3 + kx];
                        a00 = fmaf(wgt, win[ky][kx], a00);
                        a01 = fmaf(wgt, win[ky][kx + 1], a01);
                        a10 = fmaf(wgt, win[ky + 1][kx], a10);
                        a11 = fmaf(wgt, win[ky + 1][kx + 1], a11);
                    }
            }
            u16* drow = &s_d1[gl][py * T + px];
            drow[0] = f2bf(a00); drow[1] = f2bf(a01);
            drow[T] = f2bf(a10); drow[T + 1] = f2bf(a11);
        }
        __syncthreads();

        // ---- Phase B2: d3 = depthwise 3x3 over d3a, one task per thread ----
        {
            int gl = tid >> 6, patch = tid & 63;
            int py = (patch >> 3) * 2, px = (patch & 7) * 2;
            float bias = s_b3b[gl];
            float a00 = bias, a01 = bias, a10 = bias, a11 = bias;
            float win[4][4];
            const u32* base = (const u32*)&s_d3a[gl][0];
#pragma unroll
            for (int r = 0; r < 4; ++r) {
                int e = (py + r) * R18 + px;   // even
                u32 u0 = base[e >> 1];
                u32 u1 = base[(e >> 1) + 1];
                win[r][0] = bflo(u0); win[r][1] = bfhi(u0);
                win[r][2] = bflo(u1); win[r][3] = bfhi(u1);
            }
#pragma unroll
            for (int ky = 0; ky < 3; ++ky)
#pragma unroll
                for (int kx = 0; kx < 3; ++kx) {
                    float wgt = s_wd3b[gl][ky * 3 + kx];
                    a00 = fmaf(wgt, win[ky][kx], a00);
                    a01 = fmaf(wgt, win[ky][kx + 1], a01);
                    a10 = fmaf(wgt, win[ky + 1][kx], a10);
                    a11 = fmaf(wgt, win[ky + 1][kx + 1], a11);
                }
            u16* drow = &s_d3[gl][py * T + px];
            drow[0] = f2bf(a00); drow[1] = f2bf(a01);
            drow[T] = f2bf(a10); drow[T + 1] = f2bf(a11);
        }
        __syncthreads();

        // ---- Phase C: gating + project_out, packed FMA ---------------------
        //   half0: d1 gates -> ch 0..31, half1: d3 gates -> ch 32..63.
        //   acc2[o] covers out channels (ob+2o, ob+2o+1); w from s_woutT[c][o]
        //   rows (uniform-addr broadcast, 8B-aligned thanks to pad 66).
        {
            const u16* sD = (half == 0) ? &s_d1[0][0] : &s_d3[0][0];
#pragma unroll
            for (int jp = 0; jp < 2; ++jp) {
                int j0 = 2 * jp;
                float ga = gelu_fast(bf2f(sD[j0 * 256 + pix]))
                         * bf2f(sD[(j0 + 4) * 256 + pix]);
                float gb = gelu_fast(bf2f(sD[(j0 + 1) * 256 + pix]))
                         * bf2f(sD[(j0 + 5) * 256 + pix]);
                int c = c0 + j0;   // even
                const float* wc0 = &s_woutT[(c + 0) * 66 + ob];
                const float* wc1 = &s_woutT[(c + 1) * 66 + ob];
                f32x2 ga2 = {ga, ga}, gb2 = {gb, gb};
#pragma unroll
                for (int o = 0; o < 16; ++o) {
                    f32x2 w0 = *(const f32x2*)(wc0 + 2 * o);
                    f32x2 w1 = *(const f32x2*)(wc1 + 2 * o);
                    acc2[o] = __builtin_elementwise_fma(w0, ga2, acc2[o]);
                    acc2[o] = __builtin_elementwise_fma(w1, gb2, acc2[o]);
                }
            }
        }
    }

    // ---- Epilogue: bias + fp32 store --------------------------------------
    {
        int py = pix >> 4, pxx = pix & 15;
        size_t obase = (size_t)b * 64 * HW + (size_t)ob * HW
                     + (size_t)(oy0 + py) * 256 + (ox0 + pxx);
#pragma unroll
        for (int o = 0; o < 16; ++o) {
            outp[obase + (size_t)(2 * o + 0) * HW] = acc2[o][0] + b_out[ob + 2 * o + 0];
            outp[obase + (size_t)(2 * o + 1) * HW] = acc2[o][1] + b_out[ob + 2 * o + 1];
        }
    }
}

// ---------------------------------------------------------------------------
// Fallback: fully-fused kernel (used only if ws_size < 201 MB).
// ---------------------------------------------------------------------------
__global__ __launch_bounds__(256, 2)
void ffd_fused(const float* __restrict__ xin, const float* __restrict__ pnin,
               const float* __restrict__ w_in, const float* __restrict__ b_in,
               const float* __restrict__ w_pn, const float* __restrict__ b_pn,
               const float* __restrict__ w_dw1, const float* __restrict__ b_dw1,
               const float* __restrict__ w_dw3a, const float* __restrict__ b_dw3a,
               const float* __restrict__ w_dw3b, const float* __restrict__ b_dw3b,
               const float* __restrict__ w_out, const float* __restrict__ b_out,
               float* __restrict__ outp)
{
    __shared__ __align__(8) u16 s_xc[24][R20 * R20];
    __shared__ __align__(8) float s_d3a[8][R18 * R18];
    __shared__ float s_d1[8][T * T];
    __shared__ float s_d3[8][T * T];
    __shared__ float s_wd1[8][27];
    __shared__ float s_wd3a[8][27];
    __shared__ float s_wd3b[8][9];
    __shared__ float s_b1[8], s_b3a[8], s_b3b[8];

    const int tid = threadIdx.x;
    const int ox0 = blockIdx.x * T;
    const int oy0 = blockIdx.y * T;
    const int b   = blockIdx.z;

    float accL[32], accH[32];
#pragma unroll
    for (int o = 0; o < 32; ++o) { accL[o] = 0.f; accH[o] = 0.f; }

    for (int chunk = 0; chunk < 16; ++chunk) {
        const int c0 = chunk * 4;
        __syncthreads();

        for (int t = tid; t < 512; t += 256) {
            if (t < 216) {
                int gl = t / 27, idx = t - gl * 27;
                int g = (gl < 4) ? (c0 + gl) : (c0 + 60 + gl);
                s_wd1[gl][idx] = w_dw1[g * 27 + idx];
            } else if (t < 432) {
                int t2 = t - 216;
                int gl = t2 / 27, idx = t2 - gl * 27;
                int g = (gl < 4) ? (c0 + gl) : (c0 + 60 + gl);
                s_wd3a[gl][idx] = w_dw3a[g * 27 + idx];
            } else if (t < 504) {
                int t2 = t - 432;
                int gl = t2 / 9, idx = t2 - gl * 9;
                int g = (gl < 4) ? (c0 + gl) : (c0 + 60 + gl);
                s_wd3b[gl][idx] = w_dw3b[g * 9 + idx];
            } else {
                int gl = t - 504;
                int g = (gl < 4) ? (c0 + gl) : (c0 + 60 + gl);
                s_b1[gl]  = b_dw1[g];
                s_b3a[gl] = b_dw3a[g];
                s_b3b[gl] = b_dw3b[g];
            }
        }

        for (int p = tid; p < R20 * R20; p += 256) {
            int py = p / R20, px = p - py * R20;
            int gy = oy0 - 2 + py, gx = ox0 - 2 + px;
            if ((unsigned)gy >= 256u || (unsigned)gx >= 256u) {
#pragma unroll 1
                for (int l = 0; l < 24; ++l) s_xc[l][p] = 0;
                continue;
            }
            const int off = gy * 256 + gx;
            float xr[64];
            const float* xp = xin + (size_t)b * 64 * HW + off;
#pragma unroll
            for (int c = 0; c < 64; ++c) xr[c] = xp[(size_t)c * HW];
            float p0 = 0.f, p1 = 0.f;
            if (3 * c0 < 128) {
                const float* pp = pnin + (size_t)b * 2 * HW + off;
                p0 = pp[0]; p1 = pp[HW];
            }
#pragma unroll 1
            for (int l = 0; l < 24; ++l) {
                int k = (l < 12) ? (3 * c0 + l) : (3 * c0 + 192 + (l - 12));
                float acc;
                if (k < 128) {
                    acc = b_pn[k] + w_pn[2 * k] * p0 + w_pn[2 * k + 1] * p1;
                } else {
                    int kk = k - 128;
                    acc = b_in[kk];
                    const float2* wr = (const float2*)(w_in + kk * 64);
#pragma unroll
                    for (int i = 0; i < 32; ++i) {
                        float2 w2 = wr[i];
                        acc = fmaf(w2.x, xr[2 * i], acc);
                        acc = fmaf(w2.y, xr[2 * i + 1], acc);
                    }
                }
                s_xc[l][p] = f2bf(acc);
            }
        }
        __syncthreads();

        for (int task = tid; task < 8 * 81; task += 256) {
            int gl = task / 81, patch = task - gl * 81;
            int py = (patch / 9) * 2, px = (patch - (patch / 9) * 9) * 2;
            float bias = s_b3a[gl];
            float a00 = bias, a01 = bias, a10 = bias, a11 = bias;
#pragma unroll
            for (int j = 0; j < 3; ++j) {
                int lc = (gl < 4) ? (3 * gl + j) : (12 + 3 * (gl - 4) + j);
                const u32* base = (const u32*)&s_xc[lc][0];
                float win[4][4];
#pragma unroll
                for (int r = 0; r < 4; ++r) {
                    int e = (py + r) * R20 + px;
                    u32 u0 = base[e >> 1];
                    u32 u1 = base[(e >> 1) + 1];
                    win[r][0] = bflo(u0); win[r][1] = bfhi(u0);
                    win[r][2] = bflo(u1); win[r][3] = bfhi(u1);
                }
#pragma unroll
                for (int ky = 0; ky < 3; ++ky)
#pragma unroll
                    for (int kx = 0; kx < 3; ++kx) {
                        float wgt = s_wd3a[gl][j * 9 + ky * 3 + kx];
                        a00 = fmaf(wgt, win[ky][kx], a00);
                        a01 = fmaf(wgt, win[ky][kx + 1], a01);
                        a10 = fmaf(wgt, win[ky + 1][kx], a10);
                        a11 = fmaf(wgt, win[ky + 1][kx + 1], a11);
                    }
            }
            int gy0 = oy0 - 1 + py, gx0 = ox0 - 1 + px;
            bool vy0 = (unsigned)gy0 < 256u, vy1 = (unsigned)(gy0 + 1) < 256u;
            bool vx0 = (unsigned)gx0 < 256u, vx1 = (unsigned)(gx0 + 1) < 256u;
            float* drow = &s_d3a[gl][py * R18 + px];
            drow[0]       = (vy0 && vx0) ? a00 : 0.f;
            drow[1]       = (vy0 && vx1) ? a01 : 0.f;
            drow[R18]     = (vy1 && vx0) ? a10 : 0.f;
            drow[R18 + 1] = (vy1 && vx1) ? a11 : 0.f;
        }

        for (int task = tid; task < 8 * 64; task += 256) {
            int gl = task >> 6, patch = task & 63;
            int py = (patch >> 3) * 2, px = (patch & 7) * 2;
            float bias = s_b1[gl];
            float a00 = bias, a01 = bias, a10 = bias, a11 = bias;
#pragma unroll
            for (int j = 0; j < 3; ++j) {
                int lc = (gl < 4) ? (3 * gl + j) : (12 + 3 * (gl - 4) + j);
                const u32* base = (const u32*)&s_xc[lc][0];
                float win[4][4];
#pragma unroll
                for (int r = 0; r < 4; ++r) {
                    int e = (py + 1 + r) * R20 + px;
                    u32 u0 = base[e >> 1];
                    u32 u1 = base[(e >> 1) + 1];
                    u32 u2 = base[(e >> 1) + 2];
                    win[r][0] = bfhi(u0); win[r][1] = bflo(u1);
                    win[r][2] = bfhi(u1); win[r][3] = bflo(u2);
                }
#pragma unroll
                for (int ky = 0; ky < 3; ++ky)
#pragma unroll
                    for (int kx = 0; kx < 3; ++kx) {
                        float wgt = s_wd1[gl][j * 9 + ky * 3 + kx];
                        a00 = fmaf(wgt, win[ky][kx], a00);
                        a01 = fmaf(wgt, win[ky][kx + 1], a01);
                        a10 = fmaf(wgt, win[ky + 1][kx], a10);
                        a11 = fmaf(wgt, win[ky + 1][kx + 1], a11);
                    }
            }
            float* drow = &s_d1[gl][py * T + px];
            drow[0] = a00; drow[1] = a01; drow[T] = a10; drow[T + 1] = a11;
        }
        __syncthreads();

        for (int task = tid; task < 8 * 64; task += 256) {
            int gl = task >> 6, patch = task & 63;
            int py = (patch >> 3) * 2, px = (patch & 7) * 2;
            float bias = s_b3b[gl];
            float a00 = bias, a01 = bias, a10 = bias, a11 = bias;
            float win[4][4];
#pragma unroll
            for (int r = 0; r < 4; ++r) {
                int e = (py + r) * R18 + px;
                float2 f0 = *(const float2*)&s_d3a[gl][e];
                float2 f1 = *(const float2*)&s_d3a[gl][e + 2];
                win[r][0] = f0.x; win[r][1] = f0.y;
                win[r][2] = f1.x; win[r][3] = f1.y;
            }
#pragma unroll
            for (int ky = 0; ky < 3; ++ky)
#pragma unroll
                for (int kx = 0; kx < 3; ++kx) {
                    float wgt = s_wd3b[gl][ky * 3 + kx];
                    a00 = fmaf(wgt, win[ky][kx], a00);
                    a01 = fmaf(wgt, win[ky][kx + 1], a01);
                    a10 = fmaf(wgt, win[ky + 1][kx], a10);
                    a11 = fmaf(wgt, win[ky + 1][kx + 1], a11);
                }
            float* drow = &s_d3[gl][py * T + px];
            drow[0] = a00; drow[1] = a01; drow[T] = a10; drow[T + 1] = a11;
        }
        __syncthreads();

#pragma unroll
        for (int jp = 0; jp < 2; ++jp) {
            int j0 = 2 * jp;
            float g1a = gelu_exact(s_d1[j0][tid])     * s_d1[j0 + 4][tid];
            float g1b = gelu_exact(s_d1[j0 + 1][tid]) * s_d1[j0 + 5][tid];
            float g2a = gelu_exact(s_d3[j0][tid])     * s_d3[j0 + 4][tid];
            float g2b = gelu_exact(s_d3[j0 + 1][tid]) * s_d3[j0 + 5][tid];
            int c = c0 + j0;
#pragma unroll
            for (int o = 0; o < 32; ++o) {
                float2 wL = *(const float2*)(w_out + o * 64 + c);
                accL[o] = fmaf(wL.x, g1a, accL[o]);
                accL[o] = fmaf(wL.y, g1b, accL[o]);
                float2 wH = *(const float2*)(w_out + (o + 32) * 64 + c);
                accH[o] = fmaf(wH.x, g2a, accH[o]);
                accH[o] = fmaf(wH.y, g2b, accH[o]);
            }
        }
    }

    {
        int py = tid >> 4, pxx = tid & 15;
        size_t obase = (size_t)b * 64 * HW
                     + (size_t)(oy0 + py) * 256 + (ox0 + pxx);
#pragma unroll
        for (int o = 0; o < 32; ++o) {
            outp[obase + (size_t)o * HW]        = accL[o] + b_out[o];
            outp[obase + (size_t)(o + 32) * HW] = accH[o] + b_out[o + 32];
        }
    }
}

extern "C" void kernel_launch(void* const* d_in, const int* in_sizes, int n_in,
                              void* d_out, int out_size, void* d_ws, size_t ws_size,
                              hipStream_t stream) {
    (void)in_sizes; (void)n_in; (void)out_size;
    const float* xin    = (const float*)d_in[0];
    const float* pnin   = (const float*)d_in[1];
    const float* w_in   = (const float*)d_in[2];
    const float* b_in   = (const float*)d_in[3];
    const float* w_pn   = (const float*)d_in[4];
    const float* b_pn   = (const float*)d_in[5];
    const float* w_dw1  = (const float*)d_in[6];
    const float* b_dw1  = (const float*)d_in[7];
    const float* w_dw3a = (const float*)d_in[8];
    const float* b_dw3a = (const float*)d_in[9];
    const float* w_dw3b = (const float*)d_in[10];
    const float* b_dw3b = (const float*)d_in[11];
    const float* w_out  = (const float*)d_in[12];
    const float* b_out  = (const float*)d_in[13];
    float* outp = (float*)d_out;

    if (ws_size >= XC_BYTES) {
        u16* xc = (u16*)d_ws;
        dim3 g1(1024, 4), b1(256);   // 64 px/block, MFMA split-bf16
        k1_proj_mfma<<<g1, b1, 0, stream>>>(xin, pnin, w_in, b_in, w_pn, b_pn, xc);
        dim3 g2(16, 16, 4), b2(512);
        k2_spatial<<<g2, b2, 0, stream>>>(xc, w_dw1, b_dw1, w_dw3a, b_dw3a,
                                          w_dw3b, b_dw3b, w_out, b_out, outp);
    } else {
        dim3 grid(16, 16, 4), blk(256);
        ffd_fused<<<grid, blk, 0, stream>>>(xin, pnin, w_in, b_in, w_pn, b_pn,
                                            w_dw1, b_dw1, w_dw3a, b_dw3a,
                                            w_dw3b, b_dw3b, w_out, b_out, outp);
    }
}